// Round 9
// baseline (264.065 us; speedup 1.0000x reference)
//
#include <hip/hip_runtime.h>
#include <hip/hip_cooperative_groups.h>
#include <math.h>

namespace cg = cooperative_groups;

#define BB 4
#define CC 256
#define LL 4096
#define DD 32   // q/k channels
#define LOG2E 1.44269504088896f

typedef __attribute__((ext_vector_type(8))) short short8;   // 8 bf16 (4 VGPRs)
typedef __attribute__((ext_vector_type(4))) float f32x4;
typedef __attribute__((ext_vector_type(16))) float f32x16;  // 32x32 accumulator
typedef __attribute__((ext_vector_type(4))) unsigned int uint4v;

// raw workgroup barrier: waits LDS ops only — global prefetches stay in flight
#define BARRIER() asm volatile("s_waitcnt lgkmcnt(0)\n\ts_barrier" ::: "memory")

__device__ inline float fast_exp2(float x) {
#if __has_builtin(__builtin_amdgcn_exp2f)
  return __builtin_amdgcn_exp2f(x);
#else
  return exp2f(x);
#endif
}

// pack 8 f32 (reg-order r0..r7 of a 32x32 D half) into one 16B granule word via
// cvt_pk(RNE) + permlane32_swap — layout verified on-silicon in R12's producer.
#define PACK8_STORE(EX0,EX1,EX2,EX3,EX4,EX5,EX6,EX7, DSTPTR)                         \
  {                                                                                  \
    unsigned pw0, pw1, pw2, pw3;                                                     \
    asm("v_cvt_pk_bf16_f32 %0, %1, %2" : "=v"(pw0) : "v"(EX0), "v"(EX1));            \
    asm("v_cvt_pk_bf16_f32 %0, %1, %2" : "=v"(pw1) : "v"(EX2), "v"(EX3));            \
    asm("v_cvt_pk_bf16_f32 %0, %1, %2" : "=v"(pw2) : "v"(EX4), "v"(EX5));            \
    asm("v_cvt_pk_bf16_f32 %0, %1, %2" : "=v"(pw3) : "v"(EX6), "v"(EX7));            \
    asm("v_permlane32_swap_b32 %0, %1" : "+v"(pw0), "+v"(pw2));                      \
    asm("v_permlane32_swap_b32 %0, %1" : "+v"(pw1), "+v"(pw3));                      \
    uint4v pu; pu.x = pw0; pu.y = pw1; pu.z = pw2; pu.w = pw3;                       \
    *(uint4v*)(DSTPTR) = pu;                                                         \
  }

// ---------------- kernel 0: W -> 32x32-granule layout (unchanged) ----------------
// wf[tile(10)][chunk(16)][lane(64)][8]: element = W*[o = lane&31][cin = 16c+8hi+j].
// tile 0 = Wq (x log2e), 1 = Wk, 2..9 = Wv 32-ch tiles.
__global__ __launch_bounds__(256) void wprep_kernel(
    const float* __restrict__ Wq, const float* __restrict__ Wk, const float* __restrict__ Wv,
    unsigned short* __restrict__ wf)
{
  const int t = threadIdx.x;
  const int g = blockIdx.x * 4 + (t >> 6);        // granule 0..159
  const int lane = t & 63, ql = lane & 31, hi = lane >> 5;
  const int tile = g >> 4, chunk = g & 15;
  const int cin = chunk * 16 + hi * 8;
  const float* src;
  float sc = 1.0f;
  if (tile == 0)      { src = Wq + (size_t)ql * CC; sc = LOG2E; }
  else if (tile == 1) { src = Wk + (size_t)ql * CC; }
  else                { src = Wv + (size_t)(32 * (tile - 2) + ql) * CC; }
  const f32x4 a = *(const f32x4*)(src + cin);
  const f32x4 b2 = *(const f32x4*)(src + cin + 4);
  const float f0 = a[0] * sc, f1 = a[1] * sc, f2 = a[2] * sc, f3 = a[3] * sc;
  const float f4 = b2[0] * sc, f5 = b2[1] * sc, f6 = b2[2] * sc, f7 = b2[3] * sc;
  unsigned w0, w1, w2, w3;
  asm("v_cvt_pk_bf16_f32 %0, %1, %2" : "=v"(w0) : "v"(f0), "v"(f1));
  asm("v_cvt_pk_bf16_f32 %0, %1, %2" : "=v"(w1) : "v"(f2), "v"(f3));
  asm("v_cvt_pk_bf16_f32 %0, %1, %2" : "=v"(w2) : "v"(f4), "v"(f5));
  asm("v_cvt_pk_bf16_f32 %0, %1, %2" : "=v"(w3) : "v"(f6), "v"(f7));
  uint4v u; u.x = w0; u.y = w1; u.z = w2; u.w = w3;
  *(uint4v*)(wf + ((size_t)g * 64 + lane) * 8) = u;
}

// ---------------- fused kernel: QKV phase -> grid.sync -> attention phase ----------------
// R15: cooperative, grid 256 x 768 (1 block/CU). Phase 1 computes this block's own
// 64-query/64-key qF/kF/vF fragments (R13 GEMM mapped to 12 waves). grid.sync makes all
// kF/vF globally visible. Phase 2 is R14's attn verbatim.
__global__ __launch_bounds__(768, 3) void fused_kernel(
    const float* __restrict__ x, const unsigned short* __restrict__ wf,
    const float* __restrict__ bq, const float* __restrict__ bk, const float* __restrict__ bv,
    unsigned short* __restrict__ qF, unsigned short* __restrict__ kF,
    unsigned short* __restrict__ vF, const float* __restrict__ gamma_p,
    float* __restrict__ out)
{
  __shared__ union __align__(16) {
    unsigned short xb[2 * 16 * 64 * 8];                 // 32 KB (phase 1: x granules)
    struct {
      unsigned short P[2 * 8 * 2 * 2 * 512];            // 64 KB P ring
      float l[8][2][64];                                // 4 KB partial l
    } a;
  } sm;

  const int t = threadIdx.x;
  const int w = t >> 6, lane = t & 63, ql = lane & 31, hi = lane >> 5;
  const int blk = blockIdx.x;
  const int b  = (blk & 7) >> 1;                        // XCD-batch affinity
  const int it = ((blk >> 3) << 1) + (blk & 1);         // 0..63 (64-q tile)
  const int i0 = it * 64;
  const f32x16 z16 = {0.f,0.f,0.f,0.f,0.f,0.f,0.f,0.f,0.f,0.f,0.f,0.f,0.f,0.f,0.f,0.f};

  // ================= phase 1: QKV projection for this block's 2 32-subtiles =================
  // stage x granules: waves 0-7 stage sub0 (chunks 2w,2w+1); waves 8-11 sub1 (4*(w-8)..+3)
  {
    const int nst = (w < 8) ? 2 : 4;
    const int sub = (w < 8) ? 0 : 1;
    const int c0  = (w < 8) ? 2 * w : 4 * (w - 8);
    #pragma unroll 4
    for (int e = 0; e < nst; ++e) {
      const int cc = c0 + e;
      const float* xs = x + ((size_t)(b * CC + cc * 16 + hi * 8)) * LL + i0 + sub * 32 + ql;
      float f[8];
      #pragma unroll
      for (int j = 0; j < 8; ++j) f[j] = xs[(size_t)j * LL];
      unsigned w0, w1, w2, w3;
      asm("v_cvt_pk_bf16_f32 %0, %1, %2" : "=v"(w0) : "v"(f[0]), "v"(f[1]));
      asm("v_cvt_pk_bf16_f32 %0, %1, %2" : "=v"(w1) : "v"(f[2]), "v"(f[3]));
      asm("v_cvt_pk_bf16_f32 %0, %1, %2" : "=v"(w2) : "v"(f[4]), "v"(f[5]));
      asm("v_cvt_pk_bf16_f32 %0, %1, %2" : "=v"(w3) : "v"(f[6]), "v"(f[7]));
      uint4v u; u.x = w0; u.y = w1; u.z = w2; u.w = w3;
      *(uint4v*)&sm.xb[((sub * 16 + cc) * 64 + lane) * 8] = u;
    }
  }
  __syncthreads();

  if (w < 8) {
    // V-tile m = w, both subtiles
    const float bvv = bv[32 * w + ql];
    #pragma unroll
    for (int sub = 0; sub < 2; ++sub) {
      f32x16 D = z16;
      #pragma unroll
      for (int c = 0; c < 16; ++c) {
        const short8 xc = *(const short8*)&sm.xb[((sub * 16 + c) * 64 + lane) * 8];
        const short8 wv = *(const short8*)(wf + ((size_t)((2 + w) * 16 + c) * 64 + lane) * 8);
        D = __builtin_amdgcn_mfma_f32_32x32x16_bf16(xc, wv, D, 0, 0, 0);
      }
      #pragma unroll
      for (int r = 0; r < 16; ++r) D[r] += bvv;
      // sub s2: regs 8*s2.. = keys 16*s2.. -> vF granule kg = 4*it + 2*sub + s2, m = w
      #pragma unroll
      for (int s2 = 0; s2 < 2; ++s2) {
        unsigned short* dst =
            vF + (((size_t)(b * 256 + 4 * it + 2 * sub + s2) * 8 + w) * 64 + lane) * 8;
        PACK8_STORE(D[8*s2+0], D[8*s2+1], D[8*s2+2], D[8*s2+3],
                    D[8*s2+4], D[8*s2+5], D[8*s2+6], D[8*s2+7], dst);
      }
    }
  } else {
    // Q/K unit: wq = w-8: sub = wq>>1, which = wq&1 (0 = Q, 1 = K)
    const int wq = w - 8, sub = wq >> 1, which = wq & 1;
    const float* bsrc = which ? bk : bq;
    const float bscale = which ? 1.0f : LOG2E;
    float br[16];
    #pragma unroll
    for (int r = 0; r < 16; ++r)
      br[r] = bsrc[(r & 3) + 8 * (r >> 2) + 4 * hi] * bscale;
    f32x16 D = z16;
    #pragma unroll
    for (int c = 0; c < 16; ++c) {
      const short8 xc = *(const short8*)&sm.xb[((sub * 16 + c) * 64 + lane) * 8];
      const short8 wa = *(const short8*)(wf + ((size_t)(which * 16 + c) * 64 + lane) * 8);
      D = __builtin_amdgcn_mfma_f32_32x32x16_bf16(wa, xc, D, 0, 0, 0);
    }
    #pragma unroll
    for (int r = 0; r < 16; ++r) D[r] += br[r];
    unsigned short* basef = which ? kF : qF;
    const int tile32 = 2 * it + sub;
    #pragma unroll
    for (int s2 = 0; s2 < 2; ++s2) {
      unsigned short* dst = basef + (((size_t)(b * 128 + tile32) * 2 + s2) * 64 + lane) * 8;
      PACK8_STORE(D[8*s2+0], D[8*s2+1], D[8*s2+2], D[8*s2+3],
                  D[8*s2+4], D[8*s2+5], D[8*s2+6], D[8*s2+7], dst);
    }
  }

  __threadfence();
  cg::this_grid().sync();   // all kF/vF/qF visible grid-wide; xb dead -> P may alias

  // ================= phase 2: flash attention (R14 body) =================
  if (w < 8) {
    // producer: key-tile kk = pw of each window
    const int pw = w;
    short8 qB[2][2];
    #pragma unroll
    for (int qt = 0; qt < 2; ++qt)
      #pragma unroll
      for (int c = 0; c < 2; ++c)
        qB[qt][c] = *(const short8*)(qF +
            (((size_t)(b * 128 + it * 2 + qt) * 2 + c) * 64 + lane) * 8);
    short8 kA[2];
    #pragma unroll
    for (int c = 0; c < 2; ++c)
      kA[c] = *(const short8*)(kF + (((size_t)(b * 128 + pw) * 2 + c) * 64 + lane) * 8);
    float l_r[2] = {0.f, 0.f};

    auto produce = [&](int ss, int buf) {
      f32x16 S[2];
      __builtin_amdgcn_s_setprio(1);
      #pragma unroll
      for (int qt = 0; qt < 2; ++qt)
        S[qt] = __builtin_amdgcn_mfma_f32_32x32x16_bf16(kA[0], qB[qt][0], z16, 0, 0, 0);
      #pragma unroll
      for (int qt = 0; qt < 2; ++qt)
        S[qt] = __builtin_amdgcn_mfma_f32_32x32x16_bf16(kA[1], qB[qt][1], S[qt], 0, 0, 0);
      __builtin_amdgcn_s_setprio(0);
      const int ntile = ((ss + 1) & 15) * 8 + pw;
      #pragma unroll
      for (int c = 0; c < 2; ++c)
        kA[c] = *(const short8*)(kF + (((size_t)(b * 128 + ntile) * 2 + c) * 64 + lane) * 8);
      #pragma unroll
      for (int qt = 0; qt < 2; ++qt) {
        float ex[16];
        #pragma unroll
        for (int r = 0; r < 16; ++r) ex[r] = fast_exp2(S[qt][r]);
        l_r[qt] += ((((ex[0] + ex[1]) + (ex[2] + ex[3])) + ((ex[4] + ex[5]) + (ex[6] + ex[7])))
                 + (((ex[8] + ex[9]) + (ex[10] + ex[11])) + ((ex[12] + ex[13]) + (ex[14] + ex[15]))));
        #pragma unroll
        for (int c = 0; c < 2; ++c) {
          unsigned short* dst =
              &sm.a.P[(((buf * 8 + pw) * 2 + qt) * 2 + c) * 512 + hi * 256 + ql * 8];
          PACK8_STORE(ex[8*c+0], ex[8*c+1], ex[8*c+2], ex[8*c+3],
                      ex[8*c+4], ex[8*c+5], ex[8*c+6], ex[8*c+7], dst);
        }
      }
    };

    produce(0, 0);
    __syncthreads();   // P(0) ready
    for (int i = 0; i < 16; ++i) {
      if (i < 15) produce(i + 1, (i + 1) & 1);
      BARRIER();
    }
    sm.a.l[pw][0][lane] = l_r[0];
    sm.a.l[pw][1][lane] = l_r[1];
    BARRIER();
  } else {
    // consumer: ch 64*mq..+63 over ALL keys
    const int mq = w - 8;
    const unsigned short* vroot = vF + (size_t)b * (256 * 8 * 512) + lane * 8;
    f32x16 O[2][2];
    #pragma unroll
    for (int mi = 0; mi < 2; ++mi)
      #pragma unroll
      for (int qt = 0; qt < 2; ++qt) O[mi][qt] = z16;
    short8 vA[8][2];                      // 8-slot ring: ~512 issue-cyc lookahead
    #pragma unroll
    for (int s = 0; s < 8; ++s)
      #pragma unroll
      for (int mi = 0; mi < 2; ++mi)
        vA[s][mi] = *(const short8*)(vroot + ((size_t)(s * 8 + 2 * mq + mi)) * 512);
    __syncthreads();   // P(0) ready

    short8 pb[3][2];
    for (int i = 0; i < 16; ++i) {
      const int buf = i & 1;
      #pragma unroll
      for (int s = 0; s < 2; ++s)
        #pragma unroll
        for (int qt = 0; qt < 2; ++qt)
          pb[s][qt] = *(const short8*)(&sm.a.P[((((buf * 8 + 0) * 2 + qt) * 2 + s) * 512)
                                               + hi * 256 + ql * 8]);
      #pragma unroll
      for (int s = 0; s < 16; ++s) {      // step s: kk = s>>1, c = s&1
        if (s < 14) {
          const int ns = s + 2, kk = ns >> 1, c = ns & 1;
          #pragma unroll
          for (int qt = 0; qt < 2; ++qt)
            pb[ns % 3][qt] = *(const short8*)(&sm.a.P[((((buf * 8 + kk) * 2 + qt) * 2 + c) * 512)
                                                      + hi * 256 + ql * 8]);
        }
        __builtin_amdgcn_s_setprio(1);
        #pragma unroll
        for (int mi = 0; mi < 2; ++mi)
          #pragma unroll
          for (int qt = 0; qt < 2; ++qt)
            O[mi][qt] = __builtin_amdgcn_mfma_f32_32x32x16_bf16(vA[s & 7][mi], pb[s % 3][qt],
                                                                O[mi][qt], 0, 0, 0);
        __builtin_amdgcn_s_setprio(0);
        const int kg = (i * 16 + s + 8) & 255;
        #pragma unroll
        for (int mi = 0; mi < 2; ++mi)
          vA[s & 7][mi] = *(const short8*)(vroot + ((size_t)(kg * 8 + 2 * mq + mi)) * 512);
      }
      BARRIER();
    }
    BARRIER();   // l visible

    // epilogue: normalize + residual
    const float gam = gamma_p[0];
    float inv_l[2];
    #pragma unroll
    for (int qt = 0; qt < 2; ++qt) {
      float s = 0.f;
      #pragma unroll
      for (int pw = 0; pw < 8; ++pw)
        s += sm.a.l[pw][qt][ql] + sm.a.l[pw][qt][ql + 32];
      inv_l[qt] = 1.0f / s;
    }
    #pragma unroll
    for (int mi = 0; mi < 2; ++mi)
      #pragma unroll
      for (int qt = 0; qt < 2; ++qt)
        #pragma unroll
        for (int r = 0; r < 16; ++r) {
          const int ch = 64 * mq + 32 * mi + (r & 3) + 8 * (r >> 2) + 4 * hi;
          const int ii = i0 + 32 * qt + ql;
          const size_t idx = ((size_t)b * CC + ch) * LL + ii;
          out[idx] = gam * O[mi][qt][r] * inv_l[qt] + x[idx];
        }
  }
}

extern "C" void kernel_launch(void* const* d_in, const int* in_sizes, int n_in,
                              void* d_out, int out_size, void* d_ws, size_t ws_size,
                              hipStream_t stream) {
  const float* x     = (const float*)d_in[0];
  const float* Wq    = (const float*)d_in[1];
  const float* bq    = (const float*)d_in[2];
  const float* Wk    = (const float*)d_in[3];
  const float* bk    = (const float*)d_in[4];
  const float* Wv    = (const float*)d_in[5];
  const float* bv    = (const float*)d_in[6];
  const float* gamma = (const float*)d_in[7];
  float* out = (float*)d_out;

  // ws: qF (1MB) | kF (1MB) | vF (8MB) — all 32x32-fragment-linear bf16
  unsigned short* qF = (unsigned short*)d_ws;
  unsigned short* kF = qF + (size_t)BB * LL * DD;
  unsigned short* vF = kF + (size_t)BB * LL * DD;
  // wf (160KB granules) lives in d_out; consumed by fused phase 1, then overwritten
  unsigned short* wf = (unsigned short*)d_out;
  const unsigned short* wf_c = wf;

  wprep_kernel<<<40, 256, 0, stream>>>(Wq, Wk, Wv, wf);

  void* args[] = {(void*)&x, (void*)&wf_c, (void*)&bq, (void*)&bk, (void*)&bv,
                  (void*)&qF, (void*)&kF, (void*)&vF, (void*)&gamma, (void*)&out};
  hipLaunchCooperativeKernel((const void*)fused_kernel, dim3(256), dim3(768),
                             args, 0, stream);
}

// Round 10
// 136.298 us; speedup vs baseline: 1.9374x; 1.9374x over previous
//
#include <hip/hip_runtime.h>
#include <math.h>

#define BB 4
#define CC 256
#define LL 4096
#define DD 32   // q/k channels
#define LOG2E 1.44269504088896f

typedef __attribute__((ext_vector_type(8))) short short8;   // 8 bf16 (4 VGPRs)
typedef __attribute__((ext_vector_type(4))) float f32x4;
typedef __attribute__((ext_vector_type(16))) float f32x16;  // 32x32 accumulator
typedef __attribute__((ext_vector_type(4))) unsigned int uint4v;

// raw workgroup barrier: waits LDS ops only — global prefetches stay in flight
#define BARRIER() asm volatile("s_waitcnt lgkmcnt(0)\n\ts_barrier" ::: "memory")

__device__ inline float fast_exp2(float x) {
#if __has_builtin(__builtin_amdgcn_exp2f)
  return __builtin_amdgcn_exp2f(x);
#else
  return exp2f(x);
#endif
}

// pack 8 f32 (reg-order r0..r7 of a 32x32 D half) into one 16B granule word via
// cvt_pk(RNE) + permlane32_swap — layout verified on-silicon in R12's producer.
#define PACK8_STORE(EX0,EX1,EX2,EX3,EX4,EX5,EX6,EX7, DSTPTR)                         \
  {                                                                                  \
    unsigned pw0, pw1, pw2, pw3;                                                     \
    asm("v_cvt_pk_bf16_f32 %0, %1, %2" : "=v"(pw0) : "v"(EX0), "v"(EX1));            \
    asm("v_cvt_pk_bf16_f32 %0, %1, %2" : "=v"(pw1) : "v"(EX2), "v"(EX3));            \
    asm("v_cvt_pk_bf16_f32 %0, %1, %2" : "=v"(pw2) : "v"(EX4), "v"(EX5));            \
    asm("v_cvt_pk_bf16_f32 %0, %1, %2" : "=v"(pw3) : "v"(EX6), "v"(EX7));            \
    asm("v_permlane32_swap_b32 %0, %1" : "+v"(pw0), "+v"(pw2));                      \
    asm("v_permlane32_swap_b32 %0, %1" : "+v"(pw1), "+v"(pw3));                      \
    uint4v pu; pu.x = pw0; pu.y = pw1; pu.z = pw2; pu.w = pw3;                       \
    *(uint4v*)(DSTPTR) = pu;                                                         \
  }

// ---------------- kernel 0: W -> 32x32-granule layout (unchanged) ----------------
// wf[tile(10)][chunk(16)][lane(64)][8]: element = W*[o = lane&31][cin = 16c+8hi+j].
// tile 0 = Wq (x log2e), 1 = Wk, 2..9 = Wv 32-ch tiles.
__global__ __launch_bounds__(256) void wprep_kernel(
    const float* __restrict__ Wq, const float* __restrict__ Wk, const float* __restrict__ Wv,
    unsigned short* __restrict__ wf)
{
  const int t = threadIdx.x;
  const int g = blockIdx.x * 4 + (t >> 6);        // granule 0..159
  const int lane = t & 63, ql = lane & 31, hi = lane >> 5;
  const int tile = g >> 4, chunk = g & 15;
  const int cin = chunk * 16 + hi * 8;
  const float* src;
  float sc = 1.0f;
  if (tile == 0)      { src = Wq + (size_t)ql * CC; sc = LOG2E; }
  else if (tile == 1) { src = Wk + (size_t)ql * CC; }
  else                { src = Wv + (size_t)(32 * (tile - 2) + ql) * CC; }
  const f32x4 a = *(const f32x4*)(src + cin);
  const f32x4 b2 = *(const f32x4*)(src + cin + 4);
  const float f0 = a[0] * sc, f1 = a[1] * sc, f2 = a[2] * sc, f3 = a[3] * sc;
  const float f4 = b2[0] * sc, f5 = b2[1] * sc, f6 = b2[2] * sc, f7 = b2[3] * sc;
  unsigned w0, w1, w2, w3;
  asm("v_cvt_pk_bf16_f32 %0, %1, %2" : "=v"(w0) : "v"(f0), "v"(f1));
  asm("v_cvt_pk_bf16_f32 %0, %1, %2" : "=v"(w1) : "v"(f2), "v"(f3));
  asm("v_cvt_pk_bf16_f32 %0, %1, %2" : "=v"(w2) : "v"(f4), "v"(f5));
  asm("v_cvt_pk_bf16_f32 %0, %1, %2" : "=v"(w3) : "v"(f6), "v"(f7));
  uint4v u; u.x = w0; u.y = w1; u.z = w2; u.w = w3;
  *(uint4v*)(wf + ((size_t)g * 64 + lane) * 8) = u;
}

// ---------------- kernel 1: QKV projection, 32x32 MFMA, fragment-direct ----------------
// (unchanged from R13/R14)
__global__ __launch_bounds__(512, 4) void qkv_kernel(
    const float* __restrict__ x, const unsigned short* __restrict__ wf,
    const float* __restrict__ bq, const float* __restrict__ bk, const float* __restrict__ bv,
    unsigned short* __restrict__ qF, unsigned short* __restrict__ kF,
    unsigned short* __restrict__ vF)
{
  __shared__ __align__(16) unsigned short xb[16 * 64 * 8];   // 16 chunks x 1KB granules

  const int t = threadIdx.x;
  const int w = t >> 6, lane = t & 63, ql = lane & 31, hi = lane >> 5;
  const int blk = blockIdx.x;
  const int b  = (blk & 7) >> 1;                   // XCD-batch affinity
  const int it = ((blk >> 3) << 1) + (blk & 1);    // 0..127 (32-i tile)
  const int i0 = it * 32;

  // ---- stage x -> xb granules: wave w covers chunks 2w, 2w+1 ----
  #pragma unroll
  for (int e = 0; e < 2; ++e) {
    const int cc = 2 * w + e;
    const float* xs = x + ((size_t)(b * CC + cc * 16 + hi * 8)) * LL + i0 + ql;
    float f[8];
    #pragma unroll
    for (int j = 0; j < 8; ++j) f[j] = xs[(size_t)j * LL];
    unsigned w0, w1, w2, w3;
    asm("v_cvt_pk_bf16_f32 %0, %1, %2" : "=v"(w0) : "v"(f[0]), "v"(f[1]));
    asm("v_cvt_pk_bf16_f32 %0, %1, %2" : "=v"(w1) : "v"(f[2]), "v"(f[3]));
    asm("v_cvt_pk_bf16_f32 %0, %1, %2" : "=v"(w2) : "v"(f[4]), "v"(f[5]));
    asm("v_cvt_pk_bf16_f32 %0, %1, %2" : "=v"(w3) : "v"(f[6]), "v"(f[7]));
    uint4v u; u.x = w0; u.y = w1; u.z = w2; u.w = w3;
    *(uint4v*)&xb[(cc * 64 + lane) * 8] = u;
  }
  __syncthreads();

  const f32x16 z16 = {0.f,0.f,0.f,0.f,0.f,0.f,0.f,0.f,0.f,0.f,0.f,0.f,0.f,0.f,0.f,0.f};

  // ---- V tile m = w: D = x-frag(A: rows i) x Wv-frag(B: cols ch) ----
  {
    f32x16 D = z16;
    #pragma unroll
    for (int c = 0; c < 16; ++c) {
      const short8 xc = *(const short8*)&xb[(c * 64 + lane) * 8];
      const short8 wv = *(const short8*)(wf + ((size_t)((2 + w) * 16 + c) * 64 + lane) * 8);
      D = __builtin_amdgcn_mfma_f32_32x32x16_bf16(xc, wv, D, 0, 0, 0);
    }
    const float bvv = bv[32 * w + ql];   // lane = ch: one bias for all regs
    #pragma unroll
    for (int r = 0; r < 16; ++r) D[r] += bvv;
    // sub s: regs 8s..8s+7 = keys 16s..16s+15 -> vF granule (kg = 2*it+s, m = w)
    #pragma unroll
    for (int s = 0; s < 2; ++s) {
      unsigned short* dst = vF + (((size_t)(b * 256 + 2 * it + s) * 8 + w) * 64 + lane) * 8;
      PACK8_STORE(D[8*s+0], D[8*s+1], D[8*s+2], D[8*s+3],
                  D[8*s+4], D[8*s+5], D[8*s+6], D[8*s+7], dst);
    }
  }

  // ---- Q (wave 0) / K (wave 1): D = W-frag(A: rows ch) x x-frag(B: cols i) ----
  if (w < 2) {
    const float* bsrc = w ? bk : bq;
    const float bscale = w ? 1.0f : LOG2E;
    float br[16];
    #pragma unroll
    for (int r = 0; r < 16; ++r)
      br[r] = bsrc[(r & 3) + 8 * (r >> 2) + 4 * hi] * bscale;
    f32x16 D = z16;
    #pragma unroll
    for (int c = 0; c < 16; ++c) {
      const short8 xc = *(const short8*)&xb[(c * 64 + lane) * 8];
      const short8 wa = *(const short8*)(wf + ((size_t)(w * 16 + c) * 64 + lane) * 8);
      D = __builtin_amdgcn_mfma_f32_32x32x16_bf16(wa, xc, D, 0, 0, 0);
    }
    #pragma unroll
    for (int r = 0; r < 16; ++r) D[r] += br[r];
    unsigned short* basef = w ? kF : qF;
    // sub s: regs 8s..8s+7 = ch 16s..16s+15 -> granule (tile it, chunk s)
    #pragma unroll
    for (int s = 0; s < 2; ++s) {
      unsigned short* dst = basef + (((size_t)(b * 128 + it) * 2 + s) * 64 + lane) * 8;
      PACK8_STORE(D[8*s+0], D[8*s+1], D[8*s+2], D[8*s+3],
                  D[8*s+4], D[8*s+5], D[8*s+6], D[8*s+7], dst);
    }
  }
}

// ---------------- kernel 2: flash attention, 32x32 MFMA, 8P + 8C ----------------
// R16: 1024 thr = 16 waves, 1 block/CU. Per SIMD: 2 producers + 2 CONSUMERS (R14 had 1C)
// -> consumer stalls (vA residual latency, O dep-chain) overlap across the C pair.
// Producer pw (w<8): key-tile kk=pw per window, identical to R14.
// Consumer m8 = w-8 (0..7): 32 ch (granule m8), ALL keys — vA L2 traffic unchanged
// (each vF granule read exactly once per block). O[2 qt] = 32 VGPR; vA 8-ring 32;
// pb 24 -> ~105 total, under the 128 cap at (1024,4). No cross-wave O combine.
__global__ __launch_bounds__(1024, 4) void attn_kernel(
    const unsigned short* __restrict__ qF, const unsigned short* __restrict__ kF,
    const unsigned short* __restrict__ vF, const float* __restrict__ x,
    const float* __restrict__ gamma_p, float* __restrict__ out)
{
  __shared__ __align__(16) unsigned short P[2 * 8 * 2 * 2 * 512];  // 64 KB ring (2 bufs)
  __shared__ float l_lds[8][2][64];                                // [pw][qt][lane] 4 KB

  const int t = threadIdx.x;
  const int w = t >> 6, lane = t & 63, ql = lane & 31, hi = lane >> 5;
  const int blk = blockIdx.x;
  const int b  = (blk & 7) >> 1;                          // matches qkv affinity
  const int it = ((blk >> 3) << 1) + (blk & 1);           // 0..63
  const int i0 = it * 64;
  const f32x16 z16 = {0.f,0.f,0.f,0.f,0.f,0.f,0.f,0.f,0.f,0.f,0.f,0.f,0.f,0.f,0.f,0.f};

  if (w < 8) {
    // ================= producer: key-tile kk = pw of each window =================
    const int pw = w;
    short8 qB[2][2];
    #pragma unroll
    for (int qt = 0; qt < 2; ++qt)
      #pragma unroll
      for (int c = 0; c < 2; ++c)
        qB[qt][c] = *(const short8*)(qF +
            (((size_t)(b * 128 + it * 2 + qt) * 2 + c) * 64 + lane) * 8);
    short8 kA[2];
    #pragma unroll
    for (int c = 0; c < 2; ++c)
      kA[c] = *(const short8*)(kF + (((size_t)(b * 128 + pw) * 2 + c) * 64 + lane) * 8);
    float l_r[2] = {0.f, 0.f};

    auto produce = [&](int ss, int buf) {
      f32x16 S[2];
      __builtin_amdgcn_s_setprio(1);
      #pragma unroll
      for (int qt = 0; qt < 2; ++qt)
        S[qt] = __builtin_amdgcn_mfma_f32_32x32x16_bf16(kA[0], qB[qt][0], z16, 0, 0, 0);
      #pragma unroll
      for (int qt = 0; qt < 2; ++qt)
        S[qt] = __builtin_amdgcn_mfma_f32_32x32x16_bf16(kA[1], qB[qt][1], S[qt], 0, 0, 0);
      __builtin_amdgcn_s_setprio(0);
      // prefetch next window's kA (global; stays in flight across barrier)
      const int ntile = ((ss + 1) & 15) * 8 + pw;
      #pragma unroll
      for (int c = 0; c < 2; ++c)
        kA[c] = *(const short8*)(kF + (((size_t)(b * 128 + ntile) * 2 + c) * 64 + lane) * 8);
      // exp + pack: D row = (r&3)+8*(r>>2)+4*hi (key), col = q = l&31
      #pragma unroll
      for (int qt = 0; qt < 2; ++qt) {
        float ex[16];
        #pragma unroll
        for (int r = 0; r < 16; ++r) ex[r] = fast_exp2(S[qt][r]);
        l_r[qt] += ((((ex[0] + ex[1]) + (ex[2] + ex[3])) + ((ex[4] + ex[5]) + (ex[6] + ex[7])))
                 + (((ex[8] + ex[9]) + (ex[10] + ex[11])) + ((ex[12] + ex[13]) + (ex[14] + ex[15]))));
        #pragma unroll
        for (int c = 0; c < 2; ++c) {
          unsigned short* dst =
              &P[(((buf * 8 + pw) * 2 + qt) * 2 + c) * 512 + hi * 256 + ql * 8];
          PACK8_STORE(ex[8*c+0], ex[8*c+1], ex[8*c+2], ex[8*c+3],
                      ex[8*c+4], ex[8*c+5], ex[8*c+6], ex[8*c+7], dst);
        }
      }
    };

    produce(0, 0);
    __syncthreads();   // P(0) ready
    for (int i = 0; i < 16; ++i) {
      if (i < 15) produce(i + 1, (i + 1) & 1);
      BARRIER();
    }
    l_lds[pw][0][lane] = l_r[0];
    l_lds[pw][1][lane] = l_r[1];
    BARRIER();
  } else {
    // ================= consumer m8: ch 32*m8..+31 over ALL keys =================
    const int m8 = w - 8;
    const unsigned short* vroot = vF + (size_t)b * (256 * 8 * 512) + lane * 8;
    f32x16 O[2];                          // [qt]: ch 32*m8, q 32*qt
    O[0] = z16; O[1] = z16;
    short8 vA[8];                         // 8-slot ring [kg&7]: ~8-step lookahead
    #pragma unroll
    for (int s = 0; s < 8; ++s)
      vA[s] = *(const short8*)(vroot + ((size_t)(s * 8 + m8)) * 512);
    __syncthreads();   // P(0) ready

    short8 pb[3][2];                      // 3-slot ring [s%3][qt]
    for (int i = 0; i < 16; ++i) {
      const int buf = i & 1;
      // preload steps 0,1 (kk=0, c=0/1)
      #pragma unroll
      for (int s = 0; s < 2; ++s)
        #pragma unroll
        for (int qt = 0; qt < 2; ++qt)
          pb[s][qt] = *(const short8*)(&P[((((buf * 8 + 0) * 2 + qt) * 2 + s) * 512)
                                          + hi * 256 + ql * 8]);
      #pragma unroll
      for (int s = 0; s < 16; ++s) {      // step s: kk = s>>1, c = s&1, kg = i*16+s
        if (s < 14) {                     // prefetch pb 2 steps ahead
          const int ns = s + 2, kk = ns >> 1, c = ns & 1;
          #pragma unroll
          for (int qt = 0; qt < 2; ++qt)
            pb[ns % 3][qt] = *(const short8*)(&P[((((buf * 8 + kk) * 2 + qt) * 2 + c) * 512)
                                                 + hi * 256 + ql * 8]);
        }
        __builtin_amdgcn_s_setprio(1);
        #pragma unroll
        for (int qt = 0; qt < 2; ++qt)
          O[qt] = __builtin_amdgcn_mfma_f32_32x32x16_bf16(vA[s & 7], pb[s % 3][qt],
                                                          O[qt], 0, 0, 0);
        __builtin_amdgcn_s_setprio(0);
        // refill vA slot s&7 with key-group 8 steps ahead (wraps across windows)
        const int kg = (i * 16 + s + 8) & 255;
        vA[s & 7] = *(const short8*)(vroot + ((size_t)(kg * 8 + m8)) * 512);
      }
      BARRIER();
    }
    BARRIER();   // l_lds visible

    // ---- epilogue: this wave owns ch 32*m8..+31 over all keys -> no O combine ----
    const float gam = gamma_p[0];
    float inv_l[2];
    #pragma unroll
    for (int qt = 0; qt < 2; ++qt) {
      float s = 0.f;
      #pragma unroll
      for (int pw = 0; pw < 8; ++pw)
        s += l_lds[pw][qt][ql] + l_lds[pw][qt][ql + 32];
      inv_l[qt] = 1.0f / s;
    }
    #pragma unroll
    for (int qt = 0; qt < 2; ++qt)
      #pragma unroll
      for (int r = 0; r < 16; ++r) {
        const int ch = 32 * m8 + (r & 3) + 8 * (r >> 2) + 4 * hi;
        const int ii = i0 + 32 * qt + ql;
        const size_t idx = ((size_t)b * CC + ch) * LL + ii;
        out[idx] = gam * O[qt][r] * inv_l[qt] + x[idx];
      }
  }
}

extern "C" void kernel_launch(void* const* d_in, const int* in_sizes, int n_in,
                              void* d_out, int out_size, void* d_ws, size_t ws_size,
                              hipStream_t stream) {
  const float* x     = (const float*)d_in[0];
  const float* Wq    = (const float*)d_in[1];
  const float* bq    = (const float*)d_in[2];
  const float* Wk    = (const float*)d_in[3];
  const float* bk    = (const float*)d_in[4];
  const float* Wv    = (const float*)d_in[5];
  const float* bv    = (const float*)d_in[6];
  const float* gamma = (const float*)d_in[7];
  float* out = (float*)d_out;

  // ws: qF (1MB) | kF (1MB) | vF (8MB) — all 32x32-fragment-linear bf16
  unsigned short* qF = (unsigned short*)d_ws;
  unsigned short* kF = qF + (size_t)BB * LL * DD;
  unsigned short* vF = kF + (size_t)BB * LL * DD;
  // wf (160KB granules) lives in d_out; consumed by qkv, then attn overwrites d_out
  unsigned short* wf = (unsigned short*)d_out;

  wprep_kernel<<<40, 256, 0, stream>>>(Wq, Wk, Wv, wf);
  qkv_kernel<<<512, 512, 0, stream>>>(x, wf, bq, bk, bv, qF, kF, vF);
  attn_kernel<<<256, 1024, 0, stream>>>(qF, kF, vF, x, gamma, out);
}

// Round 11
// 129.856 us; speedup vs baseline: 2.0335x; 1.0496x over previous
//
#include <hip/hip_runtime.h>
#include <math.h>

#define BB 4
#define CC 256
#define LL 4096
#define DD 32   // q/k channels
#define LOG2E 1.44269504088896f

typedef __attribute__((ext_vector_type(8))) short short8;   // 8 bf16 (4 VGPRs)
typedef __attribute__((ext_vector_type(4))) float f32x4;
typedef __attribute__((ext_vector_type(16))) float f32x16;  // 32x32 accumulator
typedef __attribute__((ext_vector_type(4))) unsigned int uint4v;

// raw workgroup barrier: waits LDS ops only — global prefetches stay in flight
#define BARRIER() asm volatile("s_waitcnt lgkmcnt(0)\n\ts_barrier" ::: "memory")

__device__ inline float fast_exp2(float x) {
#if __has_builtin(__builtin_amdgcn_exp2f)
  return __builtin_amdgcn_exp2f(x);
#else
  return exp2f(x);
#endif
}

// pack 8 f32 (reg-order r0..r7 of a 32x32 D half) into one 16B granule word via
// cvt_pk(RNE) + permlane32_swap — layout verified on-silicon in R12's producer.
#define PACK8_STORE(EX0,EX1,EX2,EX3,EX4,EX5,EX6,EX7, DSTPTR)                         \
  {                                                                                  \
    unsigned pw0, pw1, pw2, pw3;                                                     \
    asm("v_cvt_pk_bf16_f32 %0, %1, %2" : "=v"(pw0) : "v"(EX0), "v"(EX1));            \
    asm("v_cvt_pk_bf16_f32 %0, %1, %2" : "=v"(pw1) : "v"(EX2), "v"(EX3));            \
    asm("v_cvt_pk_bf16_f32 %0, %1, %2" : "=v"(pw2) : "v"(EX4), "v"(EX5));            \
    asm("v_cvt_pk_bf16_f32 %0, %1, %2" : "=v"(pw3) : "v"(EX6), "v"(EX7));            \
    asm("v_permlane32_swap_b32 %0, %1" : "+v"(pw0), "+v"(pw2));                      \
    asm("v_permlane32_swap_b32 %0, %1" : "+v"(pw1), "+v"(pw3));                      \
    uint4v pu; pu.x = pw0; pu.y = pw1; pu.z = pw2; pu.w = pw3;                       \
    *(uint4v*)(DSTPTR) = pu;                                                         \
  }

// ---------------- kernel 0: W -> 32x32-granule layout ----------------
// wf[tile(10)][chunk(16)][lane(64)][8]: element = W*[o = lane&31][cin = 16c+8hi+j].
// tile 0 = Wq (x log2e), 1 = Wk, 2..9 = Wv 32-ch tiles.
__global__ __launch_bounds__(256) void wprep_kernel(
    const float* __restrict__ Wq, const float* __restrict__ Wk, const float* __restrict__ Wv,
    unsigned short* __restrict__ wf)
{
  const int t = threadIdx.x;
  const int g = blockIdx.x * 4 + (t >> 6);        // granule 0..159
  const int lane = t & 63, ql = lane & 31, hi = lane >> 5;
  const int tile = g >> 4, chunk = g & 15;
  const int cin = chunk * 16 + hi * 8;
  const float* src;
  float sc = 1.0f;
  if (tile == 0)      { src = Wq + (size_t)ql * CC; sc = LOG2E; }
  else if (tile == 1) { src = Wk + (size_t)ql * CC; }
  else                { src = Wv + (size_t)(32 * (tile - 2) + ql) * CC; }
  const f32x4 a = *(const f32x4*)(src + cin);
  const f32x4 b2 = *(const f32x4*)(src + cin + 4);
  const float f0 = a[0] * sc, f1 = a[1] * sc, f2 = a[2] * sc, f3 = a[3] * sc;
  const float f4 = b2[0] * sc, f5 = b2[1] * sc, f6 = b2[2] * sc, f7 = b2[3] * sc;
  unsigned w0, w1, w2, w3;
  asm("v_cvt_pk_bf16_f32 %0, %1, %2" : "=v"(w0) : "v"(f0), "v"(f1));
  asm("v_cvt_pk_bf16_f32 %0, %1, %2" : "=v"(w1) : "v"(f2), "v"(f3));
  asm("v_cvt_pk_bf16_f32 %0, %1, %2" : "=v"(w2) : "v"(f4), "v"(f5));
  asm("v_cvt_pk_bf16_f32 %0, %1, %2" : "=v"(w3) : "v"(f6), "v"(f7));
  uint4v u; u.x = w0; u.y = w1; u.z = w2; u.w = w3;
  *(uint4v*)(wf + ((size_t)g * 64 + lane) * 8) = u;
}

// ---------------- kernel 1: QKV projection, 32x32 MFMA, fragment-direct ----------------
__global__ __launch_bounds__(512, 4) void qkv_kernel(
    const float* __restrict__ x, const unsigned short* __restrict__ wf,
    const float* __restrict__ bq, const float* __restrict__ bk, const float* __restrict__ bv,
    unsigned short* __restrict__ qF, unsigned short* __restrict__ kF,
    unsigned short* __restrict__ vF)
{
  __shared__ __align__(16) unsigned short xb[16 * 64 * 8];   // 16 chunks x 1KB granules

  const int t = threadIdx.x;
  const int w = t >> 6, lane = t & 63, ql = lane & 31, hi = lane >> 5;
  const int blk = blockIdx.x;
  const int b  = (blk & 7) >> 1;                   // XCD-batch affinity
  const int it = ((blk >> 3) << 1) + (blk & 1);    // 0..127 (32-i tile)
  const int i0 = it * 32;

  // ---- stage x -> xb granules: wave w covers chunks 2w, 2w+1 ----
  #pragma unroll
  for (int e = 0; e < 2; ++e) {
    const int cc = 2 * w + e;
    const float* xs = x + ((size_t)(b * CC + cc * 16 + hi * 8)) * LL + i0 + ql;
    float f[8];
    #pragma unroll
    for (int j = 0; j < 8; ++j) f[j] = xs[(size_t)j * LL];
    unsigned w0, w1, w2, w3;
    asm("v_cvt_pk_bf16_f32 %0, %1, %2" : "=v"(w0) : "v"(f[0]), "v"(f[1]));
    asm("v_cvt_pk_bf16_f32 %0, %1, %2" : "=v"(w1) : "v"(f[2]), "v"(f[3]));
    asm("v_cvt_pk_bf16_f32 %0, %1, %2" : "=v"(w2) : "v"(f[4]), "v"(f[5]));
    asm("v_cvt_pk_bf16_f32 %0, %1, %2" : "=v"(w3) : "v"(f[6]), "v"(f[7]));
    uint4v u; u.x = w0; u.y = w1; u.z = w2; u.w = w3;
    *(uint4v*)&xb[(cc * 64 + lane) * 8] = u;
  }
  __syncthreads();

  const f32x16 z16 = {0.f,0.f,0.f,0.f,0.f,0.f,0.f,0.f,0.f,0.f,0.f,0.f,0.f,0.f,0.f,0.f};

  // ---- V tile m = w: D = x-frag(A: rows i) x Wv-frag(B: cols ch) ----
  {
    f32x16 D = z16;
    #pragma unroll
    for (int c = 0; c < 16; ++c) {
      const short8 xc = *(const short8*)&xb[(c * 64 + lane) * 8];
      const short8 wv = *(const short8*)(wf + ((size_t)((2 + w) * 16 + c) * 64 + lane) * 8);
      D = __builtin_amdgcn_mfma_f32_32x32x16_bf16(xc, wv, D, 0, 0, 0);
    }
    const float bvv = bv[32 * w + ql];   // lane = ch: one bias for all regs
    #pragma unroll
    for (int r = 0; r < 16; ++r) D[r] += bvv;
    // sub s: regs 8s..8s+7 = keys 16s..16s+15 -> vF granule (kg = 2*it+s, m = w)
    #pragma unroll
    for (int s = 0; s < 2; ++s) {
      unsigned short* dst = vF + (((size_t)(b * 256 + 2 * it + s) * 8 + w) * 64 + lane) * 8;
      PACK8_STORE(D[8*s+0], D[8*s+1], D[8*s+2], D[8*s+3],
                  D[8*s+4], D[8*s+5], D[8*s+6], D[8*s+7], dst);
    }
  }

  // ---- Q (wave 0) / K (wave 1): D = W-frag(A: rows ch) x x-frag(B: cols i) ----
  if (w < 2) {
    const float* bsrc = w ? bk : bq;
    const float bscale = w ? 1.0f : LOG2E;
    float br[16];
    #pragma unroll
    for (int r = 0; r < 16; ++r)
      br[r] = bsrc[(r & 3) + 8 * (r >> 2) + 4 * hi] * bscale;
    f32x16 D = z16;
    #pragma unroll
    for (int c = 0; c < 16; ++c) {
      const short8 xc = *(const short8*)&xb[(c * 64 + lane) * 8];
      const short8 wa = *(const short8*)(wf + ((size_t)(w * 16 + c) * 64 + lane) * 8);
      D = __builtin_amdgcn_mfma_f32_32x32x16_bf16(wa, xc, D, 0, 0, 0);
    }
    #pragma unroll
    for (int r = 0; r < 16; ++r) D[r] += br[r];
    unsigned short* basef = w ? kF : qF;
    // sub s: regs 8s..8s+7 = ch 16s..16s+15 -> granule (tile it, chunk s)
    #pragma unroll
    for (int s = 0; s < 2; ++s) {
      unsigned short* dst = basef + (((size_t)(b * 128 + it) * 2 + s) * 64 + lane) * 8;
      PACK8_STORE(D[8*s+0], D[8*s+1], D[8*s+2], D[8*s+3],
                  D[8*s+4], D[8*s+5], D[8*s+6], D[8*s+7], dst);
    }
  }
}

// ---------------- kernel 2: flash attention, 32x32 MFMA, 8P + 4C (R14 best) ----------------
// Empirical best across 10 schedule variants (45.2 us). 768 thr: 8 producers
// (QK^T 4 MFMA + 32 exp + permlane pack -> P ring), 4 consumers (64 ch each, ALL keys:
// 16 steps/window x 4 MFMA on 4 INDEPENDENT accumulators — dep-chain-safe; R16's
// 2-accumulator variant regressed 10%). vA 8-ring (R14: +2.5 us vs 4-ring).
__global__ __launch_bounds__(768, 3) void attn_kernel(
    const unsigned short* __restrict__ qF, const unsigned short* __restrict__ kF,
    const unsigned short* __restrict__ vF, const float* __restrict__ x,
    const float* __restrict__ gamma_p, float* __restrict__ out)
{
  __shared__ __align__(16) unsigned short P[2 * 8 * 2 * 2 * 512];  // 64 KB ring (2 bufs)
  __shared__ float l_lds[8][2][64];                                // [pw][qt][lane] 4 KB

  const int t = threadIdx.x;
  const int w = t >> 6, lane = t & 63, ql = lane & 31, hi = lane >> 5;
  const int blk = blockIdx.x;
  const int b  = (blk & 7) >> 1;                          // matches qkv affinity
  const int it = ((blk >> 3) << 1) + (blk & 1);           // 0..63
  const int i0 = it * 64;
  const f32x16 z16 = {0.f,0.f,0.f,0.f,0.f,0.f,0.f,0.f,0.f,0.f,0.f,0.f,0.f,0.f,0.f,0.f};

  if (w < 8) {
    // ================= producer: key-tile kk = pw of each window =================
    const int pw = w;
    short8 qB[2][2];
    #pragma unroll
    for (int qt = 0; qt < 2; ++qt)
      #pragma unroll
      for (int c = 0; c < 2; ++c)
        qB[qt][c] = *(const short8*)(qF +
            (((size_t)(b * 128 + it * 2 + qt) * 2 + c) * 64 + lane) * 8);
    short8 kA[2];
    #pragma unroll
    for (int c = 0; c < 2; ++c)
      kA[c] = *(const short8*)(kF + (((size_t)(b * 128 + pw) * 2 + c) * 64 + lane) * 8);
    float l_r[2] = {0.f, 0.f};

    auto produce = [&](int ss, int buf) {
      f32x16 S[2];
      __builtin_amdgcn_s_setprio(1);
      #pragma unroll
      for (int qt = 0; qt < 2; ++qt)
        S[qt] = __builtin_amdgcn_mfma_f32_32x32x16_bf16(kA[0], qB[qt][0], z16, 0, 0, 0);
      #pragma unroll
      for (int qt = 0; qt < 2; ++qt)
        S[qt] = __builtin_amdgcn_mfma_f32_32x32x16_bf16(kA[1], qB[qt][1], S[qt], 0, 0, 0);
      __builtin_amdgcn_s_setprio(0);
      // prefetch next window's kA (global; stays in flight across barrier)
      const int ntile = ((ss + 1) & 15) * 8 + pw;
      #pragma unroll
      for (int c = 0; c < 2; ++c)
        kA[c] = *(const short8*)(kF + (((size_t)(b * 128 + ntile) * 2 + c) * 64 + lane) * 8);
      // exp + pack: D row = (r&3)+8*(r>>2)+4*hi (key), col = q = l&31
      #pragma unroll
      for (int qt = 0; qt < 2; ++qt) {
        float ex[16];
        #pragma unroll
        for (int r = 0; r < 16; ++r) ex[r] = fast_exp2(S[qt][r]);
        l_r[qt] += ((((ex[0] + ex[1]) + (ex[2] + ex[3])) + ((ex[4] + ex[5]) + (ex[6] + ex[7])))
                 + (((ex[8] + ex[9]) + (ex[10] + ex[11])) + ((ex[12] + ex[13]) + (ex[14] + ex[15]))));
        #pragma unroll
        for (int c = 0; c < 2; ++c) {
          unsigned short* dst =
              &P[(((buf * 8 + pw) * 2 + qt) * 2 + c) * 512 + hi * 256 + ql * 8];
          PACK8_STORE(ex[8*c+0], ex[8*c+1], ex[8*c+2], ex[8*c+3],
                      ex[8*c+4], ex[8*c+5], ex[8*c+6], ex[8*c+7], dst);
        }
      }
    };

    produce(0, 0);
    __syncthreads();   // P(0) ready
    for (int i = 0; i < 16; ++i) {
      if (i < 15) produce(i + 1, (i + 1) & 1);
      BARRIER();
    }
    l_lds[pw][0][lane] = l_r[0];
    l_lds[pw][1][lane] = l_r[1];
    BARRIER();
  } else {
    // ================= consumer: ch 64*mq..+63 over ALL keys =================
    const int mq = w - 8;
    const unsigned short* vroot = vF + (size_t)b * (256 * 8 * 512) + lane * 8;
    f32x16 O[2][2];                       // [mi][qt]: 4 independent accumulators
    #pragma unroll
    for (int mi = 0; mi < 2; ++mi)
      #pragma unroll
      for (int qt = 0; qt < 2; ++qt) O[mi][qt] = z16;
    short8 vA[8][2];                      // 8-slot ring [g&7][mi]: ~512 issue-cyc lookahead
    #pragma unroll
    for (int s = 0; s < 8; ++s)
      #pragma unroll
      for (int mi = 0; mi < 2; ++mi)
        vA[s][mi] = *(const short8*)(vroot + ((size_t)(s * 8 + 2 * mq + mi)) * 512);
    __syncthreads();   // P(0) ready

    short8 pb[3][2];                      // 3-slot ring [s%3][qt]
    for (int i = 0; i < 16; ++i) {
      const int buf = i & 1;
      // preload steps 0,1 (kk=0, c=0/1)
      #pragma unroll
      for (int s = 0; s < 2; ++s)
        #pragma unroll
        for (int qt = 0; qt < 2; ++qt)
          pb[s][qt] = *(const short8*)(&P[((((buf * 8 + 0) * 2 + qt) * 2 + s) * 512)
                                          + hi * 256 + ql * 8]);
      #pragma unroll
      for (int s = 0; s < 16; ++s) {      // step s: kk = s>>1, c = s&1
        if (s < 14) {                     // prefetch pb 2 steps ahead
          const int ns = s + 2, kk = ns >> 1, c = ns & 1;
          #pragma unroll
          for (int qt = 0; qt < 2; ++qt)
            pb[ns % 3][qt] = *(const short8*)(&P[((((buf * 8 + kk) * 2 + qt) * 2 + c) * 512)
                                                 + hi * 256 + ql * 8]);
        }
        __builtin_amdgcn_s_setprio(1);
        #pragma unroll
        for (int mi = 0; mi < 2; ++mi)
          #pragma unroll
          for (int qt = 0; qt < 2; ++qt)
            O[mi][qt] = __builtin_amdgcn_mfma_f32_32x32x16_bf16(vA[s & 7][mi], pb[s % 3][qt],
                                                                O[mi][qt], 0, 0, 0);
        __builtin_amdgcn_s_setprio(0);
        // refill vA slot s&7 with key-group 8 steps ahead (wraps across windows)
        const int kg = (i * 16 + s + 8) & 255;
        #pragma unroll
        for (int mi = 0; mi < 2; ++mi)
          vA[s & 7][mi] = *(const short8*)(vroot + ((size_t)(kg * 8 + 2 * mq + mi)) * 512);
      }
      BARRIER();
    }
    BARRIER();   // l_lds visible

    // ---- epilogue: this wave owns ch 64*mq..+63 over all keys -> no O combine ----
    const float gam = gamma_p[0];
    float inv_l[2];
    #pragma unroll
    for (int qt = 0; qt < 2; ++qt) {
      float s = 0.f;
      #pragma unroll
      for (int pw = 0; pw < 8; ++pw)
        s += l_lds[pw][qt][ql] + l_lds[pw][qt][ql + 32];
      inv_l[qt] = 1.0f / s;
    }
    #pragma unroll
    for (int mi = 0; mi < 2; ++mi)
      #pragma unroll
      for (int qt = 0; qt < 2; ++qt)
        #pragma unroll
        for (int r = 0; r < 16; ++r) {
          const int ch = 64 * mq + 32 * mi + (r & 3) + 8 * (r >> 2) + 4 * hi;
          const int ii = i0 + 32 * qt + ql;
          const size_t idx = ((size_t)b * CC + ch) * LL + ii;
          out[idx] = gam * O[mi][qt][r] * inv_l[qt] + x[idx];
        }
  }
}

extern "C" void kernel_launch(void* const* d_in, const int* in_sizes, int n_in,
                              void* d_out, int out_size, void* d_ws, size_t ws_size,
                              hipStream_t stream) {
  const float* x     = (const float*)d_in[0];
  const float* Wq    = (const float*)d_in[1];
  const float* bq    = (const float*)d_in[2];
  const float* Wk    = (const float*)d_in[3];
  const float* bk    = (const float*)d_in[4];
  const float* Wv    = (const float*)d_in[5];
  const float* bv    = (const float*)d_in[6];
  const float* gamma = (const float*)d_in[7];
  float* out = (float*)d_out;

  // ws: qF (1MB) | kF (1MB) | vF (8MB) — all 32x32-fragment-linear bf16
  unsigned short* qF = (unsigned short*)d_ws;
  unsigned short* kF = qF + (size_t)BB * LL * DD;
  unsigned short* vF = kF + (size_t)BB * LL * DD;
  // wf (160KB granules) lives in d_out; consumed by qkv, then attn overwrites d_out
  unsigned short* wf = (unsigned short*)d_out;

  wprep_kernel<<<40, 256, 0, stream>>>(Wq, Wk, Wv, wf);
  qkv_kernel<<<512, 512, 0, stream>>>(x, wf, bq, bk, bv, qF, kF, vF);
  attn_kernel<<<256, 768, 0, stream>>>(qF, kF, vF, x, gamma, out);
}